// Round 7
// baseline (140.011 us; speedup 1.0000x reference)
//
#include <hip/hip_runtime.h>
#include <math.h>

// Problem constants
#define BS    2048            // batch
#define NROW  4096            // B*V = N
#define EDIM  256
#define INVT  (1.0f/0.07f)

typedef float  float4v __attribute__((ext_vector_type(4)));
typedef short  short8v __attribute__((ext_vector_type(8)));

static __device__ __forceinline__ unsigned short f2bf(float x) {
    // round-to-nearest-even f32 -> bf16 (inputs are finite)
    unsigned u = __builtin_bit_cast(unsigned, x);
    u += 0x7fffu + ((u >> 16) & 1u);
    return (unsigned short)(u >> 16);
}

static __device__ __forceinline__ void gload_lds16(const void* g, void* l) {
    __builtin_amdgcn_global_load_lds(
        (const __attribute__((address_space(1))) unsigned int*)g,
        (__attribute__((address_space(3))) unsigned int*)l, 16, 0, 0);
}

// ---------------- prep kernel: normalize + label bits + zero accumulators ----
__global__ void prep_kernel(const float* __restrict__ feat, const float* __restrict__ labels,
                            unsigned short* __restrict__ fnb, unsigned* __restrict__ bits,
                            float* __restrict__ zacc) {
    const int b = blockIdx.x, t = threadIdx.x;
    if (b < NROW) {
        int bb = b & (BS - 1);
        int v = b >> 11;
        float x = feat[(size_t)bb * (2 * EDIM) + (size_t)v * EDIM + t];
        float ss = x * x;
#pragma unroll
        for (int off = 32; off > 0; off >>= 1)
            ss += __shfl_xor(ss, off, 64);
        float nrm = fmaxf(sqrtf(ss), 1e-12f);
        fnb[(size_t)b * EDIM + t] = f2bf(x / nrm);
    } else {
        int g = (b - NROW) * 256 + t;   // 0..2047
        unsigned bb = 0;
#pragma unroll
        for (int d = 0; d < 10; ++d)
            bb |= (labels[g * 10 + d] != 0.0f ? 1u : 0u) << d;
        bits[g] = bb;
        // zero S (N*4), Num (N), Cnt (N*4), red[2], done[1] = N*9+3 words
        for (int k = g; k < NROW * 9 + 3; k += 2048) zacc[k] = 0.0f;
    }
}

// ---------------- main kernel: SYMMETRIC half-matrix + dbuf pipeline ---------
// dot[i,j,h] == dot[j,i,h]; label mask symmetric; argmax head identical.
// Compute only cells j < i; credit each cell to row i (register path, as
// before) AND to row j (column-sums -> shared slab -> block-end flush).
// Tiles kept: (bx,by) with bx >= 4*by  -> 544 of 1024 (480 fully-lower where
// j<i is all-true + 64 diagonal-crossing where the predicate masks per cell).
// Coverage: any cell (a,b) a>b has 64bx+63 >= a > b >= 256by => bx >= 4by,
// so every unordered pair lands in exactly one kept tile, predicate j<i.
// Pipeline from r6 (53.5us proven): 8 dbuf 32-row subtiles, STAGE(st+1)
// before compute(st), one barrier/subtile, (256,4), no spill.
// Col path: per js-step reduce 6 values (4 exp-sums, np, packed cnt<=64)
// over the 16 i's via shfl_xor(16,32) (quad bits), quad==0 lanes atomicAdd
// into ONE shared slab (6 KiB; cross-wave ds_add contention is rare).
// Block end: barrier + 256-thread flush, ~9 global atomics per contributing
// j (s0!=0 guard skips dead j's of crossing tiles).
// LDS 32+6=38.25 KiB -> 4 blocks/CU; 544 blocks ALL co-resident, zero tail
// (r5 lesson: multi-round grids pay per-block overhead; single round here).
// C/D layout (m89/m91): col = lane&15 (j), row = (lane>>4)*4 + reg (i).
__global__ __launch_bounds__(256, 4) void main_kernel(
    const unsigned short* __restrict__ fnb, const unsigned* __restrict__ bits,
    float* __restrict__ S, float* __restrict__ Num, float* __restrict__ Cnt) {

    __shared__ unsigned short shB[2][32 * 256];   // 2 x 16 KiB, swizzled granules
    __shared__ float    colS[256 * 5];            // per-j: S0..S3, np   (5 KiB)
    __shared__ unsigned colC[256];                // per-j: packed cnts  (1 KiB)

    const int tid  = threadIdx.x;
    const int lane = tid & 63;
    const int wave = tid >> 6;
    const int quad = lane >> 4;
    const int ml   = lane & 15;
    const int xr   = ml & 7;                   // swizzle XOR for this lane's rows

    // decode kept-tile id -> (bx, by): for chunk by, kept bx in [4*by, 64)
    int idr = blockIdx.x, by = 0;
    while (idr >= 64 - 4 * by) { idr -= 64 - 4 * by; ++by; }
    const int bx  = 4 * by + idr;
    const int i0  = bx * 64 + wave * 16;
    const int jc0 = by * 256;

    // zero the col slab (before the first barrier)
#pragma unroll
    for (int k = 0; k < 5; ++k) colS[tid + 256 * k] = 0.0f;
    colC[tid] = 0u;

    // A fragments: af[h][kk], 8 x short8 = 32 VGPRs (rows i0..i0+15)
    short8v af[4][2];
    {
        const unsigned short* ap = fnb + (size_t)(i0 + ml) * EDIM + quad * 8;
#pragma unroll
        for (int h = 0; h < 4; ++h)
#pragma unroll
            for (int kk = 0; kk < 2; ++kk)
                af[h][kk] = *(const short8v*)(ap + h * 64 + kk * 32);
    }

    unsigned ibr[4];
#pragma unroll
    for (int r = 0; r < 4; ++r)
        ibr[r] = bits[(i0 + quad * 4 + r) & (BS - 1)];

    float    Sp[4][4] = {};
    float    np[4] = {};
    unsigned cpk[4] = {};   // per row: 4 x 8-bit argmax-head counts

    // stage 32 j-rows (16 KiB) of subtile st into shB[buf]
    auto STAGE = [&](int st, int buf) {
#pragma unroll
        for (int q = 0; q < 4; ++q) {
            const int G   = tid + 256 * q;          // LDS 16B-granule index 0..1023
            const int row = G >> 5;                 // 0..31
            const int gg  = (G & 31) ^ (row & 7);   // global granule (pre-swizzled src)
            gload_lds16(fnb + (size_t)(jc0 + st * 32 + row) * EDIM + gg * 8,
                        &shB[buf][G * 8]);
        }
    };

    STAGE(0, 0);
    __syncthreads();                    // slab zeroed + subtile 0 staged

    for (int st = 0; st < 8; ++st) {
        const int cur = st & 1;
        if (st < 7) STAGE(st + 1, cur ^ 1);   // in flight during compute below
        const int j0 = jc0 + st * 32;

#pragma unroll
        for (int js = 0; js < 2; ++js) {
            const unsigned jb = bits[(j0 + js * 16 + ml) & (BS - 1)];

            float4v dacc[4];   // [h] -- live range = this js-half only
#pragma unroll
            for (int h = 0; h < 4; ++h) dacc[h] = (float4v){0.f, 0.f, 0.f, 0.f};
#pragma unroll
            for (int h = 0; h < 4; ++h)
#pragma unroll
                for (int kk = 0; kk < 2; ++kk) {
                    const int gsw = ((h * 8 + kk * 4 + quad) ^ xr) * 8;  // elem offset
                    short8v bf = *(const short8v*)(&shB[cur][(js * 16 + ml) * 256 + gsw]);
                    dacc[h] = __builtin_amdgcn_mfma_f32_16x16x32_bf16(af[h][kk], bf, dacc[h], 0, 0, 0);
                }

            const int j = j0 + js * 16 + ml;
            float cS0 = 0.f, cS1 = 0.f, cS2 = 0.f, cS3 = 0.f, cNp = 0.f;
            unsigned cCt = 0u;
#pragma unroll
            for (int r = 0; r < 4; ++r) {
                const int i = i0 + quad * 4 + r;
                const float d0 = dacc[0][r];
                const float d1 = dacc[1][r];
                const float d2 = dacc[2][r];
                const float d3 = dacc[3][r];
                // argmax, first index wins ties
                float bd = d0; int bh = 0;
                if (d1 > bd) { bd = d1; bh = 1; }
                if (d2 > bd) { bd = d2; bh = 2; }
                if (d3 > bd) { bd = d3; bh = 3; }
                const bool keep = (j < i);        // strict lower triangle only
                const float e0 = __expf(fmaf(d0, INVT, -INVT));
                const float e1 = __expf(fmaf(d1, INVT, -INVT));
                const float e2 = __expf(fmaf(d2, INVT, -INVT));
                const float e3 = __expf(fmaf(d3, INVT, -INVT));
                if (keep) {
                    Sp[r][0] += e0; Sp[r][1] += e1; Sp[r][2] += e2; Sp[r][3] += e3;
                    cS0 += e0; cS1 += e1; cS2 += e2; cS3 += e3;
                }
                if (keep && (ibr[r] & jb)) {
                    np[r] += bd;  cNp += bd;       // raw dot; * INVT at flush
                    cpk[r] += 1u << (bh * 8);
                    cCt    += 1u << (bh * 8);      // per-block <= 64 per head: 8-bit safe
                }
            }
            // reduce col-sums over the 16 i's of this wave (quad bits 16,32)
            cS0 += __shfl_xor(cS0, 16, 64); cS0 += __shfl_xor(cS0, 32, 64);
            cS1 += __shfl_xor(cS1, 16, 64); cS1 += __shfl_xor(cS1, 32, 64);
            cS2 += __shfl_xor(cS2, 16, 64); cS2 += __shfl_xor(cS2, 32, 64);
            cS3 += __shfl_xor(cS3, 16, 64); cS3 += __shfl_xor(cS3, 32, 64);
            cNp += __shfl_xor(cNp, 16, 64); cNp += __shfl_xor(cNp, 32, 64);
            cCt += __shfl_xor(cCt, 16, 64); cCt += __shfl_xor(cCt, 32, 64);
            if (quad == 0) {                        // 16 lanes, 16 distinct j's
                const int jj = st * 32 + js * 16 + ml;   // j - jc0
                if (cS0 != 0.f) {
                    atomicAdd(&colS[jj * 5 + 0], cS0);
                    atomicAdd(&colS[jj * 5 + 1], cS1);
                    atomicAdd(&colS[jj * 5 + 2], cS2);
                    atomicAdd(&colS[jj * 5 + 3], cS3);
                    atomicAdd(&colS[jj * 5 + 4], cNp);
                }
                if (cCt) atomicAdd(&colC[jj], cCt);
            }
        }
        __syncthreads();   // all waves done reading shB[cur]; own STAGE(st+1) drained
    }

    // row flush: reduce the 16 lanes sharing each row, one global atomic/value
#pragma unroll
    for (int r = 0; r < 4; ++r) {
        const int i = i0 + quad * 4 + r;
        float v[9];
        v[0] = np[r];
#pragma unroll
        for (int h = 0; h < 4; ++h) v[1 + h] = Sp[r][h];
#pragma unroll
        for (int h = 0; h < 4; ++h) v[5 + h] = (float)((cpk[r] >> (8 * h)) & 255u);
#pragma unroll
        for (int k = 0; k < 9; ++k) {
            float x = v[k];
            x += __shfl_xor(x, 1, 64);
            x += __shfl_xor(x, 2, 64);
            x += __shfl_xor(x, 4, 64);
            x += __shfl_xor(x, 8, 64);
            v[k] = x;
        }
        if (ml == 0) {
            atomicAdd(&Num[i], v[0] * INVT);
#pragma unroll
            for (int h = 0; h < 4; ++h) atomicAdd(&S[i * 4 + h], v[1 + h]);
#pragma unroll
            for (int h = 0; h < 4; ++h) atomicAdd(&Cnt[i * 4 + h], v[5 + h]);
        }
    }

    // col flush: transpose contributions -> rows j of the chunk
    __syncthreads();
    {
        const int j = tid;                  // 256 threads, 256 chunk j's
        const float s0 = colS[j * 5 + 0];
        if (s0 != 0.f) {                    // crossing tiles: skip dead j's
            const int gj = jc0 + j;
            atomicAdd(&S[gj * 4 + 0], s0);
            atomicAdd(&S[gj * 4 + 1], colS[j * 5 + 1]);
            atomicAdd(&S[gj * 4 + 2], colS[j * 5 + 2]);
            atomicAdd(&S[gj * 4 + 3], colS[j * 5 + 3]);
            atomicAdd(&Num[gj], colS[j * 5 + 4] * INVT);
            const unsigned ct = colC[j];
            if (ct) {
#pragma unroll
                for (int h = 0; h < 4; ++h)
                    atomicAdd(&Cnt[gj * 4 + h], (float)((ct >> (8 * h)) & 255u));
            }
        }
    }
}

// ---------------- final reduction: 16 blocks, last block writes out --------
__global__ void final_kernel(const float* __restrict__ S, const float* __restrict__ Num,
                             const float* __restrict__ Cnt, float* __restrict__ red,
                             unsigned* __restrict__ done, float* __restrict__ out) {
    const int tid = threadIdx.x;
    const int i = blockIdx.x * 256 + tid;   // grid 16 x 256 = 4096 rows exactly
    float c = 0.f;
    float numr = Num[i];
#pragma unroll
    for (int h = 0; h < 4; ++h) {
        float sh = S[i * 4 + h];
        float ch = Cnt[i * 4 + h];
        numr -= ch * (INVT + logf(sh));
        c += ch;
    }
    float ls = 0.f, lc = 0.f;
    if (c > 0.f) { ls = -(numr / c); lc = 1.f; }

    __shared__ float rs[256], rc[256];
    rs[tid] = ls; rc[tid] = lc;
    __syncthreads();
    for (int s = 128; s > 0; s >>= 1) {
        if (tid < s) { rs[tid] += rs[tid + s]; rc[tid] += rc[tid + s]; }
        __syncthreads();
    }
    if (tid == 0) {
        atomicAdd(&red[0], rs[0]);
        atomicAdd(&red[1], rc[0]);
        __threadfence();
        if (atomicAdd(done, 1u) == 15u) {
            float s = atomicAdd(&red[0], 0.0f);
            float cc = atomicAdd(&red[1], 0.0f);
            out[0] = s / cc;
        }
    }
}

extern "C" void kernel_launch(void* const* d_in, const int* in_sizes, int n_in,
                              void* d_out, int out_size, void* d_ws, size_t ws_size,
                              hipStream_t stream) {
    const float* feat = (const float*)d_in[0];    // (2048, 2, 256) f32
    const float* labels = (const float*)d_in[1];  // (2048, 10) f32
    float* out = (float*)d_out;

    char* ws = (char*)d_ws;
    unsigned short* fnb = (unsigned short*)ws;                     // N*E bf16 (2 MB)
    float* S = (float*)(ws + (size_t)NROW * EDIM * sizeof(unsigned short));
    float* Num = S + NROW * 4;
    float* Cnt = Num + NROW;
    float* red = Cnt + NROW * 4;              // red[0]=sum, red[1]=count
    unsigned* done = (unsigned*)(red + 2);    // completion counter
    unsigned* bits = done + 1;                // BS label bitmasks

    prep_kernel<<<NROW + 8, 256, 0, stream>>>(feat, labels, fnb, bits, S);
    main_kernel<<<544, 256, 0, stream>>>(fnb, bits, S, Num, Cnt);
    final_kernel<<<16, 256, 0, stream>>>(S, Num, Cnt, red, done, out);
}

// Round 8
// 127.153 us; speedup vs baseline: 1.1011x; 1.1011x over previous
//
#include <hip/hip_runtime.h>
#include <math.h>

// Problem constants
#define BS    2048            // batch
#define NROW  4096            // B*V = N
#define EDIM  256
#define INVT  (1.0f/0.07f)

typedef float  float4v __attribute__((ext_vector_type(4)));
typedef short  short8v __attribute__((ext_vector_type(8)));

static __device__ __forceinline__ unsigned short f2bf(float x) {
    // round-to-nearest-even f32 -> bf16 (inputs are finite)
    unsigned u = __builtin_bit_cast(unsigned, x);
    u += 0x7fffu + ((u >> 16) & 1u);
    return (unsigned short)(u >> 16);
}

static __device__ __forceinline__ void gload_lds16(const void* g, void* l) {
    __builtin_amdgcn_global_load_lds(
        (const __attribute__((address_space(1))) unsigned int*)g,
        (__attribute__((address_space(3))) unsigned int*)l, 16, 0, 0);
}

// ---------------- prep kernel: normalize + label bits + zero accumulators ----
__global__ void prep_kernel(const float* __restrict__ feat, const float* __restrict__ labels,
                            unsigned short* __restrict__ fnb, unsigned* __restrict__ bits,
                            float* __restrict__ zacc) {
    const int b = blockIdx.x, t = threadIdx.x;
    if (b < NROW) {
        int bb = b & (BS - 1);
        int v = b >> 11;
        float x = feat[(size_t)bb * (2 * EDIM) + (size_t)v * EDIM + t];
        float ss = x * x;
#pragma unroll
        for (int off = 32; off > 0; off >>= 1)
            ss += __shfl_xor(ss, off, 64);
        float nrm = fmaxf(sqrtf(ss), 1e-12f);
        fnb[(size_t)b * EDIM + t] = f2bf(x / nrm);
    } else {
        int g = (b - NROW) * 256 + t;   // 0..2047
        unsigned bb = 0;
#pragma unroll
        for (int d = 0; d < 10; ++d)
            bb |= (labels[g * 10 + d] != 0.0f ? 1u : 0u) << d;
        bits[g] = bb;
        // zero S (N*4), Num (N), Cnt (N*4), red[2], done[1] = N*9+3 words
        for (int k = g; k < NROW * 9 + 3; k += 2048) zacc[k] = 0.0f;
    }
}

// ---------------- main kernel: SYMMETRIC half-matrix + dbuf pipeline ---------
// Identical to round 7 EXCEPT __launch_bounds__(256,3).  Round-7 post-mortem:
// the (256,4) 128-reg cap spilled the grown live set (VGPR read 64, FETCH
// +5MB scratch reads, VALUBusy 14%) -- symmetry was confounded, not refuted.
// (256,3) = 170-reg budget; ~90-reg live set fits with slack.  544 blocks at
// 3 blocks/CU (768 slots) is still a single co-resident round, zero tail.
// dot[i,j,h] == dot[j,i,h]; label mask symmetric; argmax head identical.
// Compute only cells j < i; credit each cell to row i (register path) AND
// row j (col-sums -> shared slab -> block-end flush).
// Tiles kept: (bx,by) with bx >= 4*by -> 544 of 1024.  Coverage: any cell
// (a,b) a>b has 64bx+63 >= a > b >= 256by => bx >= 4by; predicate j<i.
// Pipeline from r6 (53.5us proven): 8 dbuf 32-row subtiles, STAGE(st+1)
// before compute(st), one barrier/subtile.
// Global fp32 atomicAdd is memory-side (32B HBM write each; WRITE_SIZE
// matches count across r0/r5/r7): col flush ~1.2M atomics ~= 38MB, ~500GB/s,
// overlapped -- secondary.
// C/D layout (m89/m91): col = lane&15 (j), row = (lane>>4)*4 + reg (i).
__global__ __launch_bounds__(256, 3) void main_kernel(
    const unsigned short* __restrict__ fnb, const unsigned* __restrict__ bits,
    float* __restrict__ S, float* __restrict__ Num, float* __restrict__ Cnt) {

    __shared__ unsigned short shB[2][32 * 256];   // 2 x 16 KiB, swizzled granules
    __shared__ float    colS[256 * 5];            // per-j: S0..S3, np   (5 KiB)
    __shared__ unsigned colC[256];                // per-j: packed cnts  (1 KiB)

    const int tid  = threadIdx.x;
    const int lane = tid & 63;
    const int wave = tid >> 6;
    const int quad = lane >> 4;
    const int ml   = lane & 15;
    const int xr   = ml & 7;                   // swizzle XOR for this lane's rows

    // decode kept-tile id -> (bx, by): for chunk by, kept bx in [4*by, 64)
    int idr = blockIdx.x, by = 0;
    while (idr >= 64 - 4 * by) { idr -= 64 - 4 * by; ++by; }
    const int bx  = 4 * by + idr;
    const int i0  = bx * 64 + wave * 16;
    const int jc0 = by * 256;

    // zero the col slab (before the first barrier)
#pragma unroll
    for (int k = 0; k < 5; ++k) colS[tid + 256 * k] = 0.0f;
    colC[tid] = 0u;

    // A fragments: af[h][kk], 8 x short8 = 32 VGPRs (rows i0..i0+15)
    short8v af[4][2];
    {
        const unsigned short* ap = fnb + (size_t)(i0 + ml) * EDIM + quad * 8;
#pragma unroll
        for (int h = 0; h < 4; ++h)
#pragma unroll
            for (int kk = 0; kk < 2; ++kk)
                af[h][kk] = *(const short8v*)(ap + h * 64 + kk * 32);
    }

    unsigned ibr[4];
#pragma unroll
    for (int r = 0; r < 4; ++r)
        ibr[r] = bits[(i0 + quad * 4 + r) & (BS - 1)];

    float    Sp[4][4] = {};
    float    np[4] = {};
    unsigned cpk[4] = {};   // per row: 4 x 8-bit argmax-head counts

    // stage 32 j-rows (16 KiB) of subtile st into shB[buf]
    auto STAGE = [&](int st, int buf) {
#pragma unroll
        for (int q = 0; q < 4; ++q) {
            const int G   = tid + 256 * q;          // LDS 16B-granule index 0..1023
            const int row = G >> 5;                 // 0..31
            const int gg  = (G & 31) ^ (row & 7);   // global granule (pre-swizzled src)
            gload_lds16(fnb + (size_t)(jc0 + st * 32 + row) * EDIM + gg * 8,
                        &shB[buf][G * 8]);
        }
    };

    STAGE(0, 0);
    __syncthreads();                    // slab zeroed + subtile 0 staged

    for (int st = 0; st < 8; ++st) {
        const int cur = st & 1;
        if (st < 7) STAGE(st + 1, cur ^ 1);   // in flight during compute below
        const int j0 = jc0 + st * 32;

#pragma unroll
        for (int js = 0; js < 2; ++js) {
            const unsigned jb = bits[(j0 + js * 16 + ml) & (BS - 1)];

            float4v dacc[4];   // [h] -- live range = this js-half only
#pragma unroll
            for (int h = 0; h < 4; ++h) dacc[h] = (float4v){0.f, 0.f, 0.f, 0.f};
#pragma unroll
            for (int h = 0; h < 4; ++h)
#pragma unroll
                for (int kk = 0; kk < 2; ++kk) {
                    const int gsw = ((h * 8 + kk * 4 + quad) ^ xr) * 8;  // elem offset
                    short8v bf = *(const short8v*)(&shB[cur][(js * 16 + ml) * 256 + gsw]);
                    dacc[h] = __builtin_amdgcn_mfma_f32_16x16x32_bf16(af[h][kk], bf, dacc[h], 0, 0, 0);
                }

            const int j = j0 + js * 16 + ml;
            float cS0 = 0.f, cS1 = 0.f, cS2 = 0.f, cS3 = 0.f, cNp = 0.f;
            unsigned cCt = 0u;
#pragma unroll
            for (int r = 0; r < 4; ++r) {
                const int i = i0 + quad * 4 + r;
                const float d0 = dacc[0][r];
                const float d1 = dacc[1][r];
                const float d2 = dacc[2][r];
                const float d3 = dacc[3][r];
                // argmax, first index wins ties
                float bd = d0; int bh = 0;
                if (d1 > bd) { bd = d1; bh = 1; }
                if (d2 > bd) { bd = d2; bh = 2; }
                if (d3 > bd) { bd = d3; bh = 3; }
                const bool keep = (j < i);        // strict lower triangle only
                const float e0 = __expf(fmaf(d0, INVT, -INVT));
                const float e1 = __expf(fmaf(d1, INVT, -INVT));
                const float e2 = __expf(fmaf(d2, INVT, -INVT));
                const float e3 = __expf(fmaf(d3, INVT, -INVT));
                if (keep) {
                    Sp[r][0] += e0; Sp[r][1] += e1; Sp[r][2] += e2; Sp[r][3] += e3;
                    cS0 += e0; cS1 += e1; cS2 += e2; cS3 += e3;
                }
                if (keep && (ibr[r] & jb)) {
                    np[r] += bd;  cNp += bd;       // raw dot; * INVT at flush
                    cpk[r] += 1u << (bh * 8);
                    cCt    += 1u << (bh * 8);      // per-block <= 64 per head: 8-bit safe
                }
            }
            // reduce col-sums over the 16 i's of this wave (quad bits 16,32)
            cS0 += __shfl_xor(cS0, 16, 64); cS0 += __shfl_xor(cS0, 32, 64);
            cS1 += __shfl_xor(cS1, 16, 64); cS1 += __shfl_xor(cS1, 32, 64);
            cS2 += __shfl_xor(cS2, 16, 64); cS2 += __shfl_xor(cS2, 32, 64);
            cS3 += __shfl_xor(cS3, 16, 64); cS3 += __shfl_xor(cS3, 32, 64);
            cNp += __shfl_xor(cNp, 16, 64); cNp += __shfl_xor(cNp, 32, 64);
            cCt += __shfl_xor(cCt, 16, 64); cCt += __shfl_xor(cCt, 32, 64);
            if (quad == 0) {                        // 16 lanes, 16 distinct j's
                const int jj = st * 32 + js * 16 + ml;   // j - jc0
                if (cS0 != 0.f) {
                    atomicAdd(&colS[jj * 5 + 0], cS0);
                    atomicAdd(&colS[jj * 5 + 1], cS1);
                    atomicAdd(&colS[jj * 5 + 2], cS2);
                    atomicAdd(&colS[jj * 5 + 3], cS3);
                    atomicAdd(&colS[jj * 5 + 4], cNp);
                }
                if (cCt) atomicAdd(&colC[jj], cCt);
            }
        }
        __syncthreads();   // all waves done reading shB[cur]; own STAGE(st+1) drained
    }

    // row flush: reduce the 16 lanes sharing each row, one global atomic/value
#pragma unroll
    for (int r = 0; r < 4; ++r) {
        const int i = i0 + quad * 4 + r;
        float v[9];
        v[0] = np[r];
#pragma unroll
        for (int h = 0; h < 4; ++h) v[1 + h] = Sp[r][h];
#pragma unroll
        for (int h = 0; h < 4; ++h) v[5 + h] = (float)((cpk[r] >> (8 * h)) & 255u);
#pragma unroll
        for (int k = 0; k < 9; ++k) {
            float x = v[k];
            x += __shfl_xor(x, 1, 64);
            x += __shfl_xor(x, 2, 64);
            x += __shfl_xor(x, 4, 64);
            x += __shfl_xor(x, 8, 64);
            v[k] = x;
        }
        if (ml == 0) {
            atomicAdd(&Num[i], v[0] * INVT);
#pragma unroll
            for (int h = 0; h < 4; ++h) atomicAdd(&S[i * 4 + h], v[1 + h]);
#pragma unroll
            for (int h = 0; h < 4; ++h) atomicAdd(&Cnt[i * 4 + h], v[5 + h]);
        }
    }

    // col flush: transpose contributions -> rows j of the chunk
    __syncthreads();
    {
        const int j = tid;                  // 256 threads, 256 chunk j's
        const float s0 = colS[j * 5 + 0];
        if (s0 != 0.f) {                    // crossing tiles: skip dead j's
            const int gj = jc0 + j;
            atomicAdd(&S[gj * 4 + 0], s0);
            atomicAdd(&S[gj * 4 + 1], colS[j * 5 + 1]);
            atomicAdd(&S[gj * 4 + 2], colS[j * 5 + 2]);
            atomicAdd(&S[gj * 4 + 3], colS[j * 5 + 3]);
            atomicAdd(&Num[gj], colS[j * 5 + 4] * INVT);
            const unsigned ct = colC[j];
            if (ct) {
#pragma unroll
                for (int h = 0; h < 4; ++h)
                    atomicAdd(&Cnt[gj * 4 + h], (float)((ct >> (8 * h)) & 255u));
            }
        }
    }
}

// ---------------- final reduction: 16 blocks, last block writes out --------
__global__ void final_kernel(const float* __restrict__ S, const float* __restrict__ Num,
                             const float* __restrict__ Cnt, float* __restrict__ red,
                             unsigned* __restrict__ done, float* __restrict__ out) {
    const int tid = threadIdx.x;
    const int i = blockIdx.x * 256 + tid;   // grid 16 x 256 = 4096 rows exactly
    float c = 0.f;
    float numr = Num[i];
#pragma unroll
    for (int h = 0; h < 4; ++h) {
        float sh = S[i * 4 + h];
        float ch = Cnt[i * 4 + h];
        numr -= ch * (INVT + logf(sh));
        c += ch;
    }
    float ls = 0.f, lc = 0.f;
    if (c > 0.f) { ls = -(numr / c); lc = 1.f; }

    __shared__ float rs[256], rc[256];
    rs[tid] = ls; rc[tid] = lc;
    __syncthreads();
    for (int s = 128; s > 0; s >>= 1) {
        if (tid < s) { rs[tid] += rs[tid + s]; rc[tid] += rc[tid + s]; }
        __syncthreads();
    }
    if (tid == 0) {
        atomicAdd(&red[0], rs[0]);
        atomicAdd(&red[1], rc[0]);
        __threadfence();
        if (atomicAdd(done, 1u) == 15u) {
            float s = atomicAdd(&red[0], 0.0f);
            float cc = atomicAdd(&red[1], 0.0f);
            out[0] = s / cc;
        }
    }
}

extern "C" void kernel_launch(void* const* d_in, const int* in_sizes, int n_in,
                              void* d_out, int out_size, void* d_ws, size_t ws_size,
                              hipStream_t stream) {
    const float* feat = (const float*)d_in[0];    // (2048, 2, 256) f32
    const float* labels = (const float*)d_in[1];  // (2048, 10) f32
    float* out = (float*)d_out;

    char* ws = (char*)d_ws;
    unsigned short* fnb = (unsigned short*)ws;                     // N*E bf16 (2 MB)
    float* S = (float*)(ws + (size_t)NROW * EDIM * sizeof(unsigned short));
    float* Num = S + NROW * 4;
    float* Cnt = Num + NROW;
    float* red = Cnt + NROW * 4;              // red[0]=sum, red[1]=count
    unsigned* done = (unsigned*)(red + 2);    // completion counter
    unsigned* bits = done + 1;                // BS label bitmasks

    prep_kernel<<<NROW + 8, 256, 0, stream>>>(feat, labels, fnb, bits, S);
    main_kernel<<<544, 256, 0, stream>>>(fnb, bits, S, Num, Cnt);
    final_kernel<<<16, 256, 0, stream>>>(S, Num, Cnt, red, done, out);
}